// Round 8
// baseline (3464.018 us; speedup 1.0000x reference)
//
#include <hip/hip_runtime.h>

#define NSEQ 32768
#define NB 8
#define NC 16
#define CHUNK 512
#define NBLK 512          // NB * NSEQ / CHUNK
#define NTHR 256
#define NLAY 29           // gated layers 1..29

__device__ __forceinline__ float sigm_f(float x) {
    return __fdividef(1.f, 1.f + __expf(-x));
}
__device__ __forceinline__ float tanh_f(float x) {
    return __fdividef(2.f, 1.f + __expf(-2.f * x)) - 1.f;
}

// Cross-XCD-coherent accesses: agent-scope relaxed atomics (no L2 wb/inv).
__device__ __forceinline__ void st_agent(float* p, float v) {
    __hip_atomic_store(p, v, __ATOMIC_RELAXED, __HIP_MEMORY_SCOPE_AGENT);
}
__device__ __forceinline__ float ld_agent(const float* p) {
    return __hip_atomic_load((float*)p, __ATOMIC_RELAXED, __HIP_MEMORY_SCOPE_AGENT);
}
__device__ __forceinline__ void flag_set(unsigned* p) {
    __hip_atomic_store(p, 1u, __ATOMIC_RELAXED, __HIP_MEMORY_SCOPE_AGENT);
}
__device__ __forceinline__ void flag_wait(unsigned* p) {
    while (__hip_atomic_load(p, __ATOMIC_RELAXED, __HIP_MEMORY_SCOPE_AGENT) == 0u)
        __builtin_amdgcn_s_sleep(2);
}

// hG: [2 parity][NBLK][NC][CHUNK] tail-exchange (32 MiB); h^j lives in slot j&1
// hF: [NBLK][NC][CHUNK] final h (16 MiB)
// fready[i][b]: block b's layer-i tail is visible
// fack[i][b]:   block b's layer-i tail was consumed by block b+1
__global__ __launch_bounds__(NTHR, 2) void k_stack(
    const float* __restrict__ x,
    const float* __restrict__ w0, const float* __restrict__ b0,
    const float* __restrict__ wf, const float* __restrict__ bf,
    const float* __restrict__ wg, const float* __restrict__ bg,
    float* __restrict__ hG, float* __restrict__ hF,
    unsigned* __restrict__ fready, unsigned* __restrict__ fack)
{
    __shared__ float hs[2][NC][CHUNK];   // 64 KiB double-buffered h chunk
    const int b = blockIdx.x;
    const int t = threadIdx.x;
    const int chunki = b & 63;
    const int batch = b >> 6;
    const bool havL = (chunki > 0);
    const bool havR = (chunki < 63);
    const float* xb = x + (size_t)batch * NSEQ + chunki * CHUNK;
    const float inv = 1.f / 32768.f;

    // ---- layer 0: frozen round-1 math (byte-identical to round 4) ----------
#pragma unroll 1
    for (int pp = 0; pp < 2; ++pp) {
        int p = t + pp * NTHR;
        float xc = xb[p] * inv;
        float xp = (p > 0 || chunki > 0) ? xb[p - 1] * inv : 0.f;
#pragma unroll
        for (int c = 0; c < NC; c++) {
            float o = w0[c * 2] * xp + w0[c * 2 + 1] * xc + b0[c];
            hs[0][c][p] = xc + o;
        }
    }
    if (havR) {   // publish tail for layer 1 (d=2) into parity 0
        float* dst = hG + ((size_t)b) * NC * CHUNK;
#pragma unroll 1
        for (int pp = 0; pp < 2; ++pp) {
            int p = t + pp * NTHR;
            if (p >= CHUNK - 2) {
#pragma unroll
                for (int c = 0; c < NC; c++)
                    st_agent(&dst[c * CHUNK + p], hs[0][c][p]);
            }
        }
    }
    __syncthreads();   // drains vmcnt: tail stores globally visible
    if (t == 0) {
        if (havR) flag_set(&fready[0 * NBLK + b]);
        if (havL) flag_wait(&fready[0 * NBLK + (b - 1)]);
    }
    __syncthreads();

    int cur = 0, par = 0;
#pragma unroll 1
    for (int i = 1; i <= NLAY; ++i) {
        const int d = 1 << (i % 10);
        const float* wfl = wf + (size_t)(i - 1) * NC * NC * 2;
        const float* wgl = wg + (size_t)(i - 1) * NC * NC * 2;
        const float* bfl = bf + (size_t)(i - 1) * NC;
        const float* bgl = bg + (size_t)(i - 1) * NC;
        const float* hbL = hG + ((size_t)par * NBLK + (b - 1)) * NC * CHUNK;
        const int nxt = cur ^ 1;
        const int dt = (i < NLAY) ? (1 << ((i + 1) % 10)) : 0;
        float* dst = hG + ((size_t)(par ^ 1) * NBLK + b) * NC * CHUNK;
        const bool pub = (i < NLAY) && havR;

        // ---- compute h^i (frozen per-position op order, byte-identical) ----
#pragma unroll 1
        for (int pp = 0; pp < 2; ++pp) {
            const int p = t + pp * NTHR;
            float hc[NC], hp[NC];
#pragma unroll
            for (int c = 0; c < NC; c++) hc[c] = hs[cur][c][p];
            if (p >= d) {
#pragma unroll
                for (int c = 0; c < NC; c++) hp[c] = hs[cur][c][p - d];
            } else if (havL) {
#pragma unroll
                for (int c = 0; c < NC; c++)
                    hp[c] = ld_agent(&hbL[c * CHUNK + (CHUNK - d + p)]);
            } else {
#pragma unroll
                for (int c = 0; c < NC; c++) hp[c] = 0.f;
            }

            float f[NC], g[NC];
#pragma unroll
            for (int co = 0; co < NC; co++) { f[co] = bfl[co]; g[co] = bgl[co]; }

#pragma unroll
            for (int ci = 0; ci < NC; ci++) {
                float xp = hp[ci], xc = hc[ci];
#pragma unroll
                for (int co = 0; co < NC; co++) {
                    f[co] = fmaf(wfl[(co * NC + ci) * 2 + 0], xp, f[co]);
                    f[co] = fmaf(wfl[(co * NC + ci) * 2 + 1], xc, f[co]);
                    g[co] = fmaf(wgl[(co * NC + ci) * 2 + 0], xp, g[co]);
                    g[co] = fmaf(wgl[(co * NC + ci) * 2 + 1], xc, g[co]);
                }
            }

#pragma unroll
            for (int co = 0; co < NC; co++) {
                float outv = tanh_f(f[co]) * sigm_f(g[co]);
                hs[nxt][co][p] = hc[co] + outv;
            }
        }

        __syncthreads();   // bar1: hs[nxt] done; all hbL reads complete

        // ---- stage A: early ack left; 2-layer-slack gate for our publish ---
        if (t == 0) {
            if (havL) flag_set(&fack[(size_t)(i - 1) * NBLK + (b - 1)]);
            // we will overwrite slot i&1 (holds h^{i-2}); right consumed it
            // during its iteration i-1 and acked then.
            if (pub && i >= 2) flag_wait(&fack[(size_t)(i - 2) * NBLK + b]);
        }
        __syncthreads();   // bar2: gate passed for everyone

        // ---- publish h^i tail into slot i&1 --------------------------------
        if (pub) {
#pragma unroll 1
            for (int pp = 0; pp < 2; ++pp) {
                int p = t + pp * NTHR;
                if (p >= CHUNK - dt) {
#pragma unroll
                    for (int c = 0; c < NC; c++)
                        st_agent(&dst[c * CHUNK + p], hs[nxt][c][p]);
                }
            }
        }
        __syncthreads();   // bar3: publish stores drained (vmcnt before barrier)

        // ---- stage B: announce ready; wait left ready for next layer -------
        if (t == 0) {
            if (pub) flag_set(&fready[(size_t)i * NBLK + b]);
            if (i < NLAY && havL) flag_wait(&fready[(size_t)i * NBLK + (b - 1)]);
        }
        __syncthreads();   // bar4
        cur ^= 1; par ^= 1;
    }

    // ---- write h_final to hF (kernel boundary synchronizes) ----------------
    {
        float* dst = hF + (size_t)b * NC * CHUNK;
#pragma unroll 1
        for (int pp = 0; pp < 2; ++pp) {
            int p = t + pp * NTHR;
#pragma unroll
            for (int c = 0; c < NC; c++)
                dst[c * CHUNK + p] = hs[cur][c][p];
        }
    }
}

// Head: frozen round-1 math (passed every round). r = relu(h - xin);
// a = relu(wa@r+ba); o = wo@a+bo; log_softmax; mask. 64 positions per block.
__global__ __launch_bounds__(256) void k_final(
    const float* __restrict__ hbuf, const float* __restrict__ x,
    const int* __restrict__ lengths,
    const float* __restrict__ wa, const float* __restrict__ ba,
    const float* __restrict__ wo, const float* __restrict__ bo,
    float* __restrict__ out)
{
    __shared__ float s_r[64][17];
    __shared__ float s_ra[64][65];
    __shared__ float s_red[2][4][64];

    int t = threadIdx.x;
    int p = t & 63;
    int q = __builtin_amdgcn_readfirstlane(t >> 6);
    int blk = blockIdx.x;
    int batch = blk >> 9;
    int tile = blk & 511;
    int cb = batch * 64 + (tile >> 3);
    int off = (tile & 7) * 64;
    int n = tile * 64 + p;
    size_t pos = (size_t)batch * NSEQ + n;
    float xin = x[pos] * (1.f / 32768.f);

    {
        const float* rb = hbuf + (size_t)cb * NC * CHUNK + off;
#pragma unroll
        for (int cc = 0; cc < 4; ++cc) {
            int c = q * 4 + cc;
            s_r[p][c] = fmaxf(rb[(size_t)c * CHUNK + p] - xin, 0.f);
        }
    }
    __syncthreads();

    {
        float rr[NC];
#pragma unroll
        for (int c = 0; c < NC; c++) rr[c] = s_r[p][c];
#pragma unroll
        for (int jj = 0; jj < 16; jj++) {
            int j = q * 16 + jj;
            float acc = ba[j];
#pragma unroll
            for (int c = 0; c < NC; c++) acc = fmaf(wa[j * NC + c], rr[c], acc);
            s_ra[p][j] = fmaxf(acc, 0.f);
        }
    }
    __syncthreads();

    float ra[64];
#pragma unroll
    for (int j = 0; j < 64; j++) ra[j] = s_ra[p][j];

    float o[64];
    float m = -1e30f;
#pragma unroll 8
    for (int kk = 0; kk < 64; kk++) {
        int k = q * 64 + kk;
        float acc = bo[k];
#pragma unroll
        for (int j = 0; j < 64; j++) acc = fmaf(wo[k * 64 + j], ra[j], acc);
        o[kk] = acc;
        m = fmaxf(m, acc);
    }
    s_red[0][q][p] = m;
    __syncthreads();
    m = fmaxf(fmaxf(s_red[0][0][p], s_red[0][1][p]),
              fmaxf(s_red[0][2][p], s_red[0][3][p]));
    float s = 0.f;
#pragma unroll
    for (int kk = 0; kk < 64; kk++) s += __expf(o[kk] - m);
    s_red[1][q][p] = s;
    __syncthreads();
    s = s_red[1][0][p] + s_red[1][1][p] + s_red[1][2][p] + s_red[1][3][p];
    float lse = m + __logf(s);

    bool valid = n < lengths[batch];
    float* po = out + ((size_t)batch * 256 + q * 64) * NSEQ + n;
#pragma unroll
    for (int kk = 0; kk < 64; kk++) {
        float v = valid ? (o[kk] - lse) : 0.f;
        __builtin_nontemporal_store(v, &po[(size_t)kk * NSEQ]);
    }
}

extern "C" void kernel_launch(void* const* d_in, const int* in_sizes, int n_in,
                              void* d_out, int out_size, void* d_ws, size_t ws_size,
                              hipStream_t stream) {
    const float* x   = (const float*)d_in[0];
    const int* lens  = (const int*)d_in[1];
    const float* w0  = (const float*)d_in[2];
    const float* b0  = (const float*)d_in[3];
    const float* wf  = (const float*)d_in[4];
    const float* bf  = (const float*)d_in[5];
    const float* wg  = (const float*)d_in[6];
    const float* bg  = (const float*)d_in[7];
    const float* wa  = (const float*)d_in[8];
    const float* ba  = (const float*)d_in[9];
    const float* wo  = (const float*)d_in[10];
    const float* bo  = (const float*)d_in[11];
    float* out = (float*)d_out;

    float* hG = (float*)d_ws;                               // 32 MiB
    float* hF = hG + (size_t)2 * NBLK * NC * CHUNK;         // 16 MiB
    unsigned* fready = (unsigned*)(hF + (size_t)NBLK * NC * CHUNK);
    unsigned* fack   = fready + NLAY * NBLK;

    hipMemsetAsync(fready, 0, (size_t)2 * NLAY * NBLK * sizeof(unsigned), stream);

    void* args[] = {
        (void*)&x, (void*)&w0, (void*)&b0, (void*)&wf, (void*)&bf,
        (void*)&wg, (void*)&bg, (void*)&hG, (void*)&hF,
        (void*)&fready, (void*)&fack
    };
    hipLaunchCooperativeKernel((const void*)k_stack, dim3(NBLK), dim3(NTHR),
                               args, 0, stream);

    k_final<<<dim3(NB * (NSEQ / 64)), dim3(256), 0, stream>>>(
        hF, x, lens, wa, ba, wo, bo, out);
}

// Round 9
// 738.715 us; speedup vs baseline: 4.6893x; 4.6893x over previous
//
#include <hip/hip_runtime.h>

#define NSEQ 32768
#define NB 8
#define NC 16

__device__ __forceinline__ float sigm_f(float x) {
    return __fdividef(1.f, 1.f + __expf(-x));
}
__device__ __forceinline__ float tanh_f(float x) {
    return __fdividef(2.f, 1.f + __expf(-2.f * x)) - 1.f;
}

// Layer 0: h = xin + causal_conv(xin, w0, b0, d=1), xin = x/32768
__global__ __launch_bounds__(256) void k_layer0(
    const float* __restrict__ x, const float* __restrict__ w0,
    const float* __restrict__ b0, float* __restrict__ h)
{
    int tid = blockIdx.x * 256 + threadIdx.x;      // position index over B*N
    int n = tid & (NSEQ - 1);
    const float inv = 1.f / 32768.f;
    float xc = x[tid] * inv;
    float xp = (n >= 1) ? x[tid - 1] * inv : 0.f;
    float v[NC];
#pragma unroll
    for (int c = 0; c < NC; c++) {
        float o = w0[c * 2] * xp + w0[c * 2 + 1] * xc + b0[c];
        v[c] = xc + o;
    }
    float4* ph = (float4*)(h + (size_t)tid * NC);
#pragma unroll
    for (int i = 0; i < 4; i++)
        ph[i] = make_float4(v[i * 4], v[i * 4 + 1], v[i * 4 + 2], v[i * 4 + 3]);
}

// Gated layer i: h_out = h_in + tanh(f)*sigmoid(g), f/g = causal convs of h_in
__global__ __launch_bounds__(256) void k_layer(
    const float* __restrict__ hin, float* __restrict__ hout,
    const float* __restrict__ wf, const float* __restrict__ bf,
    const float* __restrict__ wg, const float* __restrict__ bg, int d)
{
    int tid = blockIdx.x * 256 + threadIdx.x;
    int n = tid & (NSEQ - 1);

    float hc[NC], hp[NC];
    {
        const float4* pc = (const float4*)(hin + (size_t)tid * NC);
#pragma unroll
        for (int i = 0; i < 4; i++) {
            float4 t = pc[i];
            hc[i * 4] = t.x; hc[i * 4 + 1] = t.y; hc[i * 4 + 2] = t.z; hc[i * 4 + 3] = t.w;
        }
    }
    if (n >= d) {
        const float4* pp = (const float4*)(hin + (size_t)(tid - d) * NC);
#pragma unroll
        for (int i = 0; i < 4; i++) {
            float4 t = pp[i];
            hp[i * 4] = t.x; hp[i * 4 + 1] = t.y; hp[i * 4 + 2] = t.z; hp[i * 4 + 3] = t.w;
        }
    } else {
#pragma unroll
        for (int i = 0; i < NC; i++) hp[i] = 0.f;
    }

    float f[NC], g[NC];
#pragma unroll
    for (int co = 0; co < NC; co++) { f[co] = bf[co]; g[co] = bg[co]; }

#pragma unroll
    for (int ci = 0; ci < NC; ci++) {
        float xp = hp[ci], xc = hc[ci];
#pragma unroll
        for (int co = 0; co < NC; co++) {
            // weights are wave-uniform -> scalar loads, 1 SGPR operand per v_fma
            f[co] = fmaf(wf[(co * NC + ci) * 2 + 0], xp, f[co]);
            f[co] = fmaf(wf[(co * NC + ci) * 2 + 1], xc, f[co]);
            g[co] = fmaf(wg[(co * NC + ci) * 2 + 0], xp, g[co]);
            g[co] = fmaf(wg[(co * NC + ci) * 2 + 1], xc, g[co]);
        }
    }

    float v[NC];
#pragma unroll
    for (int co = 0; co < NC; co++) {
        float outv = tanh_f(f[co]) * sigm_f(g[co]);
        v[co] = hc[co] + outv;
    }
    float4* po = (float4*)(hout + (size_t)tid * NC);
#pragma unroll
    for (int i = 0; i < 4; i++)
        po[i] = make_float4(v[i * 4], v[i * 4 + 1], v[i * 4 + 2], v[i * 4 + 3]);
}

// Head: agg = h_final - xin; a = relu(wa@relu(agg)+ba); o = wo@a+bo;
// log_softmax over 256 channels; mask by lengths. 64 positions per block.
// Identical to round-1 k_final except nontemporal output stores (kills RFO).
__global__ __launch_bounds__(256) void k_final(
    const float* __restrict__ hfin, const float* __restrict__ x,
    const int* __restrict__ lengths,
    const float* __restrict__ wa, const float* __restrict__ ba,
    const float* __restrict__ wo, const float* __restrict__ bo,
    float* __restrict__ out)
{
    __shared__ float s_r[64][17];    // relu(agg), odd stride: conflict-free
    __shared__ float s_ra[64][65];   // relu(a)
    __shared__ float s_red[2][4][64];

    int t = threadIdx.x;
    int p = t & 63;
    int q = __builtin_amdgcn_readfirstlane(t >> 6);   // wave index, scalar
    int blk = blockIdx.x;
    int b = blk >> 9;                 // 512 tiles of 64 per batch
    int n0 = (blk & 511) << 6;
    int n = n0 + p;
    size_t pos = (size_t)b * NSEQ + n;
    float xin = x[pos] * (1.f / 32768.f);

    // phase 1: stage relu(h - xin)
    {
        const float4* ph = (const float4*)(hfin + pos * NC);
        float4 v = ph[q];
        s_r[p][q * 4 + 0] = fmaxf(v.x - xin, 0.f);
        s_r[p][q * 4 + 1] = fmaxf(v.y - xin, 0.f);
        s_r[p][q * 4 + 2] = fmaxf(v.z - xin, 0.f);
        s_r[p][q * 4 + 3] = fmaxf(v.w - xin, 0.f);
    }
    __syncthreads();

    // phase 2: a[j] for j = q*16 .. q*16+15
    {
        float r[NC];
#pragma unroll
        for (int c = 0; c < NC; c++) r[c] = s_r[p][c];
#pragma unroll
        for (int jj = 0; jj < 16; jj++) {
            int j = q * 16 + jj;
            float acc = ba[j];
#pragma unroll
            for (int c = 0; c < NC; c++) acc = fmaf(wa[j * NC + c], r[c], acc);
            s_ra[p][j] = fmaxf(acc, 0.f);
        }
    }
    __syncthreads();

    // phase 3: o[k] for k = q*64 .. q*64+63, logsumexp across block
    float ra[64];
#pragma unroll
    for (int j = 0; j < 64; j++) ra[j] = s_ra[p][j];

    float o[64];
    float m = -1e30f;
#pragma unroll 8
    for (int kk = 0; kk < 64; kk++) {
        int k = q * 64 + kk;
        float acc = bo[k];
#pragma unroll
        for (int j = 0; j < 64; j++) acc = fmaf(wo[k * 64 + j], ra[j], acc);
        o[kk] = acc;
        m = fmaxf(m, acc);
    }
    s_red[0][q][p] = m;
    __syncthreads();
    m = fmaxf(fmaxf(s_red[0][0][p], s_red[0][1][p]),
              fmaxf(s_red[0][2][p], s_red[0][3][p]));
    float s = 0.f;
#pragma unroll
    for (int kk = 0; kk < 64; kk++) s += __expf(o[kk] - m);
    s_red[1][q][p] = s;
    __syncthreads();
    s = s_red[1][0][p] + s_red[1][1][p] + s_red[1][2][p] + s_red[1][3][p];
    float lse = m + __logf(s);

    bool valid = n < lengths[b];
    float* po = out + ((size_t)b * 256 + q * 64) * NSEQ + n;
#pragma unroll
    for (int kk = 0; kk < 64; kk++) {
        float v = valid ? (o[kk] - lse) : 0.f;
        __builtin_nontemporal_store(v, &po[(size_t)kk * NSEQ]);
    }
}

extern "C" void kernel_launch(void* const* d_in, const int* in_sizes, int n_in,
                              void* d_out, int out_size, void* d_ws, size_t ws_size,
                              hipStream_t stream) {
    const float* x   = (const float*)d_in[0];
    const int* lens  = (const int*)d_in[1];
    const float* w0  = (const float*)d_in[2];
    const float* b0  = (const float*)d_in[3];
    const float* wf  = (const float*)d_in[4];
    const float* bf  = (const float*)d_in[5];
    const float* wg  = (const float*)d_in[6];
    const float* bg  = (const float*)d_in[7];
    const float* wa  = (const float*)d_in[8];
    const float* ba  = (const float*)d_in[9];
    const float* wo  = (const float*)d_in[10];
    const float* bo  = (const float*)d_in[11];
    float* out = (float*)d_out;

    float* hA = (float*)d_ws;                          // [B][N][16]
    float* hB = hA + (size_t)NB * NSEQ * NC;           // ping-pong (32 MiB total)

    const int total = NB * NSEQ;
    dim3 blk(256);
    dim3 grd(total / 256);

    k_layer0<<<grd, blk, 0, stream>>>(x, w0, b0, hA);

    float* cur = hA;
    float* nxt = hB;
    for (int i = 1; i <= 29; i++) {
        int d = 1 << (i % 10);
        k_layer<<<grd, blk, 0, stream>>>(cur, nxt,
                                         wf + (size_t)(i - 1) * NC * NC * 2,
                                         bf + (size_t)(i - 1) * NC,
                                         wg + (size_t)(i - 1) * NC * NC * 2,
                                         bg + (size_t)(i - 1) * NC, d);
        float* tmp = cur; cur = nxt; nxt = tmp;
    }

    dim3 fgrd(NB * (NSEQ / 64));
    k_final<<<fgrd, blk, 0, stream>>>(cur, x, lens, wa, ba, wo, bo, out);
}

// Round 10
// 708.079 us; speedup vs baseline: 4.8921x; 1.0433x over previous
//
#include <hip/hip_runtime.h>

#define NSEQ 32768
#define NB 8
#define NC 16

__device__ __forceinline__ float sigm_f(float x) {
    return __fdividef(1.f, 1.f + __expf(-x));
}
__device__ __forceinline__ float tanh_f(float x) {
    return __fdividef(2.f, 1.f + __expf(-2.f * x)) - 1.f;
}

// Layer 0: h = xin + causal_conv(xin, w0, b0, d=1), xin = x/32768
// (byte-identical to round 9 — FROZEN)
__global__ __launch_bounds__(256) void k_layer0(
    const float* __restrict__ x, const float* __restrict__ w0,
    const float* __restrict__ b0, float* __restrict__ h)
{
    int tid = blockIdx.x * 256 + threadIdx.x;      // position index over B*N
    int n = tid & (NSEQ - 1);
    const float inv = 1.f / 32768.f;
    float xc = x[tid] * inv;
    float xp = (n >= 1) ? x[tid - 1] * inv : 0.f;
    float v[NC];
#pragma unroll
    for (int c = 0; c < NC; c++) {
        float o = w0[c * 2] * xp + w0[c * 2 + 1] * xc + b0[c];
        v[c] = xc + o;
    }
    float4* ph = (float4*)(h + (size_t)tid * NC);
#pragma unroll
    for (int i = 0; i < 4; i++)
        ph[i] = make_float4(v[i * 4], v[i * 4 + 1], v[i * 4 + 2], v[i * 4 + 3]);
}

// Gated layer i (byte-identical to round 9 — FROZEN)
__global__ __launch_bounds__(256) void k_layer(
    const float* __restrict__ hin, float* __restrict__ hout,
    const float* __restrict__ wf, const float* __restrict__ bf,
    const float* __restrict__ wg, const float* __restrict__ bg, int d)
{
    int tid = blockIdx.x * 256 + threadIdx.x;
    int n = tid & (NSEQ - 1);

    float hc[NC], hp[NC];
    {
        const float4* pc = (const float4*)(hin + (size_t)tid * NC);
#pragma unroll
        for (int i = 0; i < 4; i++) {
            float4 t = pc[i];
            hc[i * 4] = t.x; hc[i * 4 + 1] = t.y; hc[i * 4 + 2] = t.z; hc[i * 4 + 3] = t.w;
        }
    }
    if (n >= d) {
        const float4* pp = (const float4*)(hin + (size_t)(tid - d) * NC);
#pragma unroll
        for (int i = 0; i < 4; i++) {
            float4 t = pp[i];
            hp[i * 4] = t.x; hp[i * 4 + 1] = t.y; hp[i * 4 + 2] = t.z; hp[i * 4 + 3] = t.w;
        }
    } else {
#pragma unroll
        for (int i = 0; i < NC; i++) hp[i] = 0.f;
    }

    float f[NC], g[NC];
#pragma unroll
    for (int co = 0; co < NC; co++) { f[co] = bf[co]; g[co] = bg[co]; }

#pragma unroll
    for (int ci = 0; ci < NC; ci++) {
        float xp = hp[ci], xc = hc[ci];
#pragma unroll
        for (int co = 0; co < NC; co++) {
            // weights are wave-uniform -> scalar loads, 1 SGPR operand per v_fma
            f[co] = fmaf(wf[(co * NC + ci) * 2 + 0], xp, f[co]);
            f[co] = fmaf(wf[(co * NC + ci) * 2 + 1], xc, f[co]);
            g[co] = fmaf(wg[(co * NC + ci) * 2 + 0], xp, g[co]);
            g[co] = fmaf(wg[(co * NC + ci) * 2 + 1], xc, g[co]);
        }
    }

    float v[NC];
#pragma unroll
    for (int co = 0; co < NC; co++) {
        float outv = tanh_f(f[co]) * sigm_f(g[co]);
        v[co] = hc[co] + outv;
    }
    float4* po = (float4*)(hout + (size_t)tid * NC);
#pragma unroll
    for (int i = 0; i < 4; i++)
        po[i] = make_float4(v[i * 4], v[i * 4 + 1], v[i * 4 + 2], v[i * 4 + 3]);
}

// Head v2: 512 threads = 64 positions x 8 waves; wave q owns 32 output
// channels -> o[32] + ra[64] stay in VGPRs (round-9 spilled at 4x64).
// Per-value fmaf chains identical to rounds 1-9; only the lse s-sum grouping
// changes (8 partials vs 4) -- sub-ulp, unamplified.
__global__ __launch_bounds__(512, 2) void k_final(
    const float* __restrict__ hfin, const float* __restrict__ x,
    const int* __restrict__ lengths,
    const float* __restrict__ wa, const float* __restrict__ ba,
    const float* __restrict__ wo, const float* __restrict__ bo,
    float* __restrict__ out)
{
    __shared__ float s_r[64][17];    // relu(agg), odd stride: conflict-free
    __shared__ float s_ra[64][65];   // relu(a)
    __shared__ float s_red[2][8][64];

    int t = threadIdx.x;
    int p = t & 63;
    int q = __builtin_amdgcn_readfirstlane(t >> 6);   // wave index 0..7, scalar
    int blk = blockIdx.x;
    int b = blk >> 9;                 // 512 tiles of 64 per batch
    int n0 = (blk & 511) << 6;
    int n = n0 + p;
    size_t pos = (size_t)b * NSEQ + n;
    float xin = x[pos] * (1.f / 32768.f);

    // phase 1: waves 0-3 stage relu(h - xin) (identical math text)
    if (q < 4) {
        const float4* ph = (const float4*)(hfin + pos * NC);
        float4 v = ph[q];
        s_r[p][q * 4 + 0] = fmaxf(v.x - xin, 0.f);
        s_r[p][q * 4 + 1] = fmaxf(v.y - xin, 0.f);
        s_r[p][q * 4 + 2] = fmaxf(v.z - xin, 0.f);
        s_r[p][q * 4 + 3] = fmaxf(v.w - xin, 0.f);
    }
    __syncthreads();

    // phase 2: a[j] for j = q*8 .. q*8+7 (same per-j fmaf chain)
    {
        float r[NC];
#pragma unroll
        for (int c = 0; c < NC; c++) r[c] = s_r[p][c];
#pragma unroll
        for (int jj = 0; jj < 8; jj++) {
            int j = q * 8 + jj;
            float acc = ba[j];
#pragma unroll
            for (int c = 0; c < NC; c++) acc = fmaf(wa[j * NC + c], r[c], acc);
            s_ra[p][j] = fmaxf(acc, 0.f);
        }
    }
    __syncthreads();

    // phase 3: o[kk] for k = q*32 .. q*32+31, logsumexp across 8 waves
    float ra[64];
#pragma unroll
    for (int j = 0; j < 64; j++) ra[j] = s_ra[p][j];

    float o[32];
    float m = -1e30f;
#pragma unroll 4
    for (int kk = 0; kk < 32; kk++) {
        int k = q * 32 + kk;
        float acc = bo[k];
#pragma unroll
        for (int j = 0; j < 64; j++) acc = fmaf(wo[k * 64 + j], ra[j], acc);
        o[kk] = acc;
        m = fmaxf(m, acc);
    }
    s_red[0][q][p] = m;
    __syncthreads();
    m = fmaxf(fmaxf(fmaxf(s_red[0][0][p], s_red[0][1][p]),
                    fmaxf(s_red[0][2][p], s_red[0][3][p])),
              fmaxf(fmaxf(s_red[0][4][p], s_red[0][5][p]),
                    fmaxf(s_red[0][6][p], s_red[0][7][p])));
    float s = 0.f;
#pragma unroll
    for (int kk = 0; kk < 32; kk++) s += __expf(o[kk] - m);
    s_red[1][q][p] = s;
    __syncthreads();
    s = ((s_red[1][0][p] + s_red[1][1][p]) + (s_red[1][2][p] + s_red[1][3][p]))
      + ((s_red[1][4][p] + s_red[1][5][p]) + (s_red[1][6][p] + s_red[1][7][p]));
    float lse = m + __logf(s);

    bool valid = n < lengths[b];
    float* po = out + ((size_t)b * 256 + q * 32) * NSEQ + n;
#pragma unroll
    for (int kk = 0; kk < 32; kk++) {
        float v = valid ? (o[kk] - lse) : 0.f;
        __builtin_nontemporal_store(v, &po[(size_t)kk * NSEQ]);
    }
}

extern "C" void kernel_launch(void* const* d_in, const int* in_sizes, int n_in,
                              void* d_out, int out_size, void* d_ws, size_t ws_size,
                              hipStream_t stream) {
    const float* x   = (const float*)d_in[0];
    const int* lens  = (const int*)d_in[1];
    const float* w0  = (const float*)d_in[2];
    const float* b0  = (const float*)d_in[3];
    const float* wf  = (const float*)d_in[4];
    const float* bf  = (const float*)d_in[5];
    const float* wg  = (const float*)d_in[6];
    const float* bg  = (const float*)d_in[7];
    const float* wa  = (const float*)d_in[8];
    const float* ba  = (const float*)d_in[9];
    const float* wo  = (const float*)d_in[10];
    const float* bo  = (const float*)d_in[11];
    float* out = (float*)d_out;

    float* hA = (float*)d_ws;                          // [B][N][16]
    float* hB = hA + (size_t)NB * NSEQ * NC;           // ping-pong (32 MiB total)

    const int total = NB * NSEQ;
    dim3 blk(256);
    dim3 grd(total / 256);

    k_layer0<<<grd, blk, 0, stream>>>(x, w0, b0, hA);

    float* cur = hA;
    float* nxt = hB;
    for (int i = 1; i <= 29; i++) {
        int d = 1 << (i % 10);
        k_layer<<<grd, blk, 0, stream>>>(cur, nxt,
                                         wf + (size_t)(i - 1) * NC * NC * 2,
                                         bf + (size_t)(i - 1) * NC,
                                         wg + (size_t)(i - 1) * NC * NC * 2,
                                         bg + (size_t)(i - 1) * NC, d);
        float* tmp = cur; cur = nxt; nxt = tmp;
    }

    dim3 fgrd(NB * (NSEQ / 64));
    k_final<<<fgrd, dim3(512), 0, stream>>>(cur, x, lens, wa, ba, wo, bo, out);
}

// Round 11
// 669.962 us; speedup vs baseline: 5.1705x; 1.0569x over previous
//
#include <hip/hip_runtime.h>

#define NSEQ 32768
#define NB 8
#define NC 16
#define LBLK 1024          // layer-kernel grid (NB*NSEQ/256)
#define LPX (LBLK / 8)     // logical blocks per XCD = 128

__device__ __forceinline__ float sigm_f(float x) {
    return __fdividef(1.f, 1.f + __expf(-x));
}
__device__ __forceinline__ float tanh_f(float x) {
    return __fdividef(2.f, 1.f + __expf(-2.f * x)) - 1.f;
}

// XCD-aware swizzle: hardware dispatches blockIdx round-robin over 8 XCDs.
// lbid = (bid&7)*128 + bid>>3 puts logical blocks [x*128,(x+1)*128) — i.e.
// batch x's whole h slice (2MB r + 2MB w) — on XCD x's 4MB L2. Pure index
// permutation: per-position math and tid mapping unchanged (numerics frozen).
__device__ __forceinline__ int swz_bid() {
    int bid = blockIdx.x;
    return (bid & 7) * LPX + (bid >> 3);
}

// Layer 0: h = xin + causal_conv(xin, w0, b0, d=1), xin = x/32768
// (math text FROZEN; only block->position assignment swizzled)
__global__ __launch_bounds__(256) void k_layer0(
    const float* __restrict__ x, const float* __restrict__ w0,
    const float* __restrict__ b0, float* __restrict__ h)
{
    int tid = swz_bid() * 256 + threadIdx.x;       // position index over B*N
    int n = tid & (NSEQ - 1);
    const float inv = 1.f / 32768.f;
    float xc = x[tid] * inv;
    float xp = (n >= 1) ? x[tid - 1] * inv : 0.f;
    float v[NC];
#pragma unroll
    for (int c = 0; c < NC; c++) {
        float o = w0[c * 2] * xp + w0[c * 2 + 1] * xc + b0[c];
        v[c] = xc + o;
    }
    float4* ph = (float4*)(h + (size_t)tid * NC);
#pragma unroll
    for (int i = 0; i < 4; i++)
        ph[i] = make_float4(v[i * 4], v[i * 4 + 1], v[i * 4 + 2], v[i * 4 + 3]);
}

// Gated layer i (math text FROZEN; only block->position assignment swizzled)
__global__ __launch_bounds__(256) void k_layer(
    const float* __restrict__ hin, float* __restrict__ hout,
    const float* __restrict__ wf, const float* __restrict__ bf,
    const float* __restrict__ wg, const float* __restrict__ bg, int d)
{
    int tid = swz_bid() * 256 + threadIdx.x;
    int n = tid & (NSEQ - 1);

    float hc[NC], hp[NC];
    {
        const float4* pc = (const float4*)(hin + (size_t)tid * NC);
#pragma unroll
        for (int i = 0; i < 4; i++) {
            float4 t = pc[i];
            hc[i * 4] = t.x; hc[i * 4 + 1] = t.y; hc[i * 4 + 2] = t.z; hc[i * 4 + 3] = t.w;
        }
    }
    if (n >= d) {
        const float4* pp = (const float4*)(hin + (size_t)(tid - d) * NC);
#pragma unroll
        for (int i = 0; i < 4; i++) {
            float4 t = pp[i];
            hp[i * 4] = t.x; hp[i * 4 + 1] = t.y; hp[i * 4 + 2] = t.z; hp[i * 4 + 3] = t.w;
        }
    } else {
#pragma unroll
        for (int i = 0; i < NC; i++) hp[i] = 0.f;
    }

    float f[NC], g[NC];
#pragma unroll
    for (int co = 0; co < NC; co++) { f[co] = bf[co]; g[co] = bg[co]; }

#pragma unroll
    for (int ci = 0; ci < NC; ci++) {
        float xp = hp[ci], xc = hc[ci];
#pragma unroll
        for (int co = 0; co < NC; co++) {
            // weights are wave-uniform -> scalar loads, 1 SGPR operand per v_fma
            f[co] = fmaf(wf[(co * NC + ci) * 2 + 0], xp, f[co]);
            f[co] = fmaf(wf[(co * NC + ci) * 2 + 1], xc, f[co]);
            g[co] = fmaf(wg[(co * NC + ci) * 2 + 0], xp, g[co]);
            g[co] = fmaf(wg[(co * NC + ci) * 2 + 1], xc, g[co]);
        }
    }

    float v[NC];
#pragma unroll
    for (int co = 0; co < NC; co++) {
        float outv = tanh_f(f[co]) * sigm_f(g[co]);
        v[co] = hc[co] + outv;
    }
    float4* po = (float4*)(hout + (size_t)tid * NC);
#pragma unroll
    for (int i = 0; i < 4; i++)
        po[i] = make_float4(v[i * 4], v[i * 4 + 1], v[i * 4 + 2], v[i * 4 + 3]);
}

// Head v2 (unchanged from round 10): 512 threads, wave q owns 32 channels,
// registers not scratch; nontemporal stores.
__global__ __launch_bounds__(512, 2) void k_final(
    const float* __restrict__ hfin, const float* __restrict__ x,
    const int* __restrict__ lengths,
    const float* __restrict__ wa, const float* __restrict__ ba,
    const float* __restrict__ wo, const float* __restrict__ bo,
    float* __restrict__ out)
{
    __shared__ float s_r[64][17];    // relu(agg), odd stride: conflict-free
    __shared__ float s_ra[64][65];   // relu(a)
    __shared__ float s_red[2][8][64];

    int t = threadIdx.x;
    int p = t & 63;
    int q = __builtin_amdgcn_readfirstlane(t >> 6);   // wave index 0..7, scalar
    int blk = blockIdx.x;
    int b = blk >> 9;                 // 512 tiles of 64 per batch
    int n0 = (blk & 511) << 6;
    int n = n0 + p;
    size_t pos = (size_t)b * NSEQ + n;
    float xin = x[pos] * (1.f / 32768.f);

    // phase 1: waves 0-3 stage relu(h - xin) (identical math text)
    if (q < 4) {
        const float4* ph = (const float4*)(hfin + pos * NC);
        float4 v = ph[q];
        s_r[p][q * 4 + 0] = fmaxf(v.x - xin, 0.f);
        s_r[p][q * 4 + 1] = fmaxf(v.y - xin, 0.f);
        s_r[p][q * 4 + 2] = fmaxf(v.z - xin, 0.f);
        s_r[p][q * 4 + 3] = fmaxf(v.w - xin, 0.f);
    }
    __syncthreads();

    // phase 2: a[j] for j = q*8 .. q*8+7 (same per-j fmaf chain)
    {
        float r[NC];
#pragma unroll
        for (int c = 0; c < NC; c++) r[c] = s_r[p][c];
#pragma unroll
        for (int jj = 0; jj < 8; jj++) {
            int j = q * 8 + jj;
            float acc = ba[j];
#pragma unroll
            for (int c = 0; c < NC; c++) acc = fmaf(wa[j * NC + c], r[c], acc);
            s_ra[p][j] = fmaxf(acc, 0.f);
        }
    }
    __syncthreads();

    // phase 3: o[kk] for k = q*32 .. q*32+31, logsumexp across 8 waves
    float ra[64];
#pragma unroll
    for (int j = 0; j < 64; j++) ra[j] = s_ra[p][j];

    float o[32];
    float m = -1e30f;
#pragma unroll 4
    for (int kk = 0; kk < 32; kk++) {
        int k = q * 32 + kk;
        float acc = bo[k];
#pragma unroll
        for (int j = 0; j < 64; j++) acc = fmaf(wo[k * 64 + j], ra[j], acc);
        o[kk] = acc;
        m = fmaxf(m, acc);
    }
    s_red[0][q][p] = m;
    __syncthreads();
    m = fmaxf(fmaxf(fmaxf(s_red[0][0][p], s_red[0][1][p]),
                    fmaxf(s_red[0][2][p], s_red[0][3][p])),
              fmaxf(fmaxf(s_red[0][4][p], s_red[0][5][p]),
                    fmaxf(s_red[0][6][p], s_red[0][7][p])));
    float s = 0.f;
#pragma unroll
    for (int kk = 0; kk < 32; kk++) s += __expf(o[kk] - m);
    s_red[1][q][p] = s;
    __syncthreads();
    s = ((s_red[1][0][p] + s_red[1][1][p]) + (s_red[1][2][p] + s_red[1][3][p]))
      + ((s_red[1][4][p] + s_red[1][5][p]) + (s_red[1][6][p] + s_red[1][7][p]));
    float lse = m + __logf(s);

    bool valid = n < lengths[b];
    float* po = out + ((size_t)b * 256 + q * 32) * NSEQ + n;
#pragma unroll
    for (int kk = 0; kk < 32; kk++) {
        float v = valid ? (o[kk] - lse) : 0.f;
        __builtin_nontemporal_store(v, &po[(size_t)kk * NSEQ]);
    }
}

extern "C" void kernel_launch(void* const* d_in, const int* in_sizes, int n_in,
                              void* d_out, int out_size, void* d_ws, size_t ws_size,
                              hipStream_t stream) {
    const float* x   = (const float*)d_in[0];
    const int* lens  = (const int*)d_in[1];
    const float* w0  = (const float*)d_in[2];
    const float* b0  = (const float*)d_in[3];
    const float* wf  = (const float*)d_in[4];
    const float* bf  = (const float*)d_in[5];
    const float* wg  = (const float*)d_in[6];
    const float* bg  = (const float*)d_in[7];
    const float* wa  = (const float*)d_in[8];
    const float* ba  = (const float*)d_in[9];
    const float* wo  = (const float*)d_in[10];
    const float* bo  = (const float*)d_in[11];
    float* out = (float*)d_out;

    float* hA = (float*)d_ws;                          // [B][N][16]
    float* hB = hA + (size_t)NB * NSEQ * NC;           // ping-pong (32 MiB total)

    const int total = NB * NSEQ;
    dim3 blk(256);
    dim3 grd(total / 256);

    k_layer0<<<grd, blk, 0, stream>>>(x, w0, b0, hA);

    float* cur = hA;
    float* nxt = hB;
    for (int i = 1; i <= 29; i++) {
        int d = 1 << (i % 10);
        k_layer<<<grd, blk, 0, stream>>>(cur, nxt,
                                         wf + (size_t)(i - 1) * NC * NC * 2,
                                         bf + (size_t)(i - 1) * NC,
                                         wg + (size_t)(i - 1) * NC * NC * 2,
                                         bg + (size_t)(i - 1) * NC, d);
        float* tmp = cur; cur = nxt; nxt = tmp;
    }

    dim3 fgrd(NB * (NSEQ / 64));
    k_final<<<fgrd, dim3(512), 0, stream>>>(cur, x, lens, wa, ba, wo, bo, out);
}

// Round 12
// 638.538 us; speedup vs baseline: 5.4249x; 1.0492x over previous
//
#include <hip/hip_runtime.h>

#define NSEQ 32768
#define NB 8
#define NC 16
#define LBLK 1024          // layer0 grid (NB*NSEQ/256)
#define LPX (LBLK / 8)     // layer0 logical blocks per XCD = 128
#define QGRD 4096          // gated-layer grid (NB*NSEQ/64), 4 threads/position
#define QPX (QGRD / 8)     // gated-layer logical blocks per XCD = 512

__device__ __forceinline__ float sigm_f(float x) {
    return __fdividef(1.f, 1.f + __expf(-x));
}
__device__ __forceinline__ float tanh_f(float x) {
    return __fdividef(2.f, 1.f + __expf(-2.f * x)) - 1.f;
}

// Layer 0: h = xin + causal_conv(xin, w0, b0, d=1), xin = x/32768
// (byte-identical to round 11 — FROZEN)
__global__ __launch_bounds__(256) void k_layer0(
    const float* __restrict__ x, const float* __restrict__ w0,
    const float* __restrict__ b0, float* __restrict__ h)
{
    int bid = blockIdx.x;
    int tid = ((bid & 7) * LPX + (bid >> 3)) * 256 + threadIdx.x;
    int n = tid & (NSEQ - 1);
    const float inv = 1.f / 32768.f;
    float xc = x[tid] * inv;
    float xp = (n >= 1) ? x[tid - 1] * inv : 0.f;
    float v[NC];
#pragma unroll
    for (int c = 0; c < NC; c++) {
        float o = w0[c * 2] * xp + w0[c * 2 + 1] * xc + b0[c];
        v[c] = xc + o;
    }
    float4* ph = (float4*)(h + (size_t)tid * NC);
#pragma unroll
    for (int i = 0; i < 4; i++)
        ph[i] = make_float4(v[i * 4], v[i * 4 + 1], v[i * 4 + 2], v[i * 4 + 3]);
}

// Gated layer, channel-split x4: 4 threads per position; wave q (= t>>6,
// wave-uniform) computes output channels q*4..q*4+3. Per-value fmaf chains
// textually identical to rounds 1-11 (same ci order, same epilogue).
// Grid 4096 blocks -> 16 waves/SIMD (was 4): hides SMEM/VMEM latency.
__global__ __launch_bounds__(256) void k_layer(
    const float* __restrict__ hin, float* __restrict__ hout,
    const float* __restrict__ wf, const float* __restrict__ bf,
    const float* __restrict__ wg, const float* __restrict__ bg, int d)
{
    int bid = blockIdx.x;
    int lbid = (bid & 7) * QPX + (bid >> 3);          // XCD swizzle: batch b -> XCD b
    int t = threadIdx.x;
    int pos = lbid * 64 + (t & 63);                   // position over B*N
    int q = __builtin_amdgcn_readfirstlane(t >> 6);   // channel quarter 0..3
    int n = pos & (NSEQ - 1);

    float hc[NC], hp[NC];
    {
        const float4* pc = (const float4*)(hin + (size_t)pos * NC);
#pragma unroll
        for (int i = 0; i < 4; i++) {
            float4 tv = pc[i];
            hc[i * 4] = tv.x; hc[i * 4 + 1] = tv.y; hc[i * 4 + 2] = tv.z; hc[i * 4 + 3] = tv.w;
        }
    }
    if (n >= d) {
        const float4* pp = (const float4*)(hin + (size_t)(pos - d) * NC);
#pragma unroll
        for (int i = 0; i < 4; i++) {
            float4 tv = pp[i];
            hp[i * 4] = tv.x; hp[i * 4 + 1] = tv.y; hp[i * 4 + 2] = tv.z; hp[i * 4 + 3] = tv.w;
        }
    } else {
#pragma unroll
        for (int i = 0; i < NC; i++) hp[i] = 0.f;
    }

    const int c0 = q * 4;
    float f[4], g[4];
#pragma unroll
    for (int j = 0; j < 4; j++) { f[j] = bf[c0 + j]; g[j] = bg[c0 + j]; }

#pragma unroll
    for (int ci = 0; ci < NC; ci++) {
        float xp = hp[ci], xc = hc[ci];
#pragma unroll
        for (int j = 0; j < 4; j++) {
            int co = c0 + j;
            // weights wave-uniform -> scalar loads, SGPR operand per v_fma
            f[j] = fmaf(wf[(co * NC + ci) * 2 + 0], xp, f[j]);
            f[j] = fmaf(wf[(co * NC + ci) * 2 + 1], xc, f[j]);
            g[j] = fmaf(wg[(co * NC + ci) * 2 + 0], xp, g[j]);
            g[j] = fmaf(wg[(co * NC + ci) * 2 + 1], xc, g[j]);
        }
    }

    float v[4];
#pragma unroll
    for (int j = 0; j < 4; j++) {
        float outv = tanh_f(f[j]) * sigm_f(g[j]);
        v[j] = hc[c0 + j] + outv;
    }
    float4* po = (float4*)(hout + (size_t)pos * NC + c0);
    po[0] = make_float4(v[0], v[1], v[2], v[3]);
}

// Head v2 (unchanged from round 10): 512 threads, wave q owns 32 channels,
// registers not scratch; nontemporal stores.
__global__ __launch_bounds__(512, 2) void k_final(
    const float* __restrict__ hfin, const float* __restrict__ x,
    const int* __restrict__ lengths,
    const float* __restrict__ wa, const float* __restrict__ ba,
    const float* __restrict__ wo, const float* __restrict__ bo,
    float* __restrict__ out)
{
    __shared__ float s_r[64][17];    // relu(agg), odd stride: conflict-free
    __shared__ float s_ra[64][65];   // relu(a)
    __shared__ float s_red[2][8][64];

    int t = threadIdx.x;
    int p = t & 63;
    int q = __builtin_amdgcn_readfirstlane(t >> 6);   // wave index 0..7, scalar
    int blk = blockIdx.x;
    int b = blk >> 9;                 // 512 tiles of 64 per batch
    int n0 = (blk & 511) << 6;
    int n = n0 + p;
    size_t pos = (size_t)b * NSEQ + n;
    float xin = x[pos] * (1.f / 32768.f);

    // phase 1: waves 0-3 stage relu(h - xin) (identical math text)
    if (q < 4) {
        const float4* ph = (const float4*)(hfin + pos * NC);
        float4 v = ph[q];
        s_r[p][q * 4 + 0] = fmaxf(v.x - xin, 0.f);
        s_r[p][q * 4 + 1] = fmaxf(v.y - xin, 0.f);
        s_r[p][q * 4 + 2] = fmaxf(v.z - xin, 0.f);
        s_r[p][q * 4 + 3] = fmaxf(v.w - xin, 0.f);
    }
    __syncthreads();

    // phase 2: a[j] for j = q*8 .. q*8+7 (same per-j fmaf chain)
    {
        float r[NC];
#pragma unroll
        for (int c = 0; c < NC; c++) r[c] = s_r[p][c];
#pragma unroll
        for (int jj = 0; jj < 8; jj++) {
            int j = q * 8 + jj;
            float acc = ba[j];
#pragma unroll
            for (int c = 0; c < NC; c++) acc = fmaf(wa[j * NC + c], r[c], acc);
            s_ra[p][j] = fmaxf(acc, 0.f);
        }
    }
    __syncthreads();

    // phase 3: o[kk] for k = q*32 .. q*32+31, logsumexp across 8 waves
    float ra[64];
#pragma unroll
    for (int j = 0; j < 64; j++) ra[j] = s_ra[p][j];

    float o[32];
    float m = -1e30f;
#pragma unroll 4
    for (int kk = 0; kk < 32; kk++) {
        int k = q * 32 + kk;
        float acc = bo[k];
#pragma unroll
        for (int j = 0; j < 64; j++) acc = fmaf(wo[k * 64 + j], ra[j], acc);
        o[kk] = acc;
        m = fmaxf(m, acc);
    }
    s_red[0][q][p] = m;
    __syncthreads();
    m = fmaxf(fmaxf(fmaxf(s_red[0][0][p], s_red[0][1][p]),
                    fmaxf(s_red[0][2][p], s_red[0][3][p])),
              fmaxf(fmaxf(s_red[0][4][p], s_red[0][5][p]),
                    fmaxf(s_red[0][6][p], s_red[0][7][p])));
    float s = 0.f;
#pragma unroll
    for (int kk = 0; kk < 32; kk++) s += __expf(o[kk] - m);
    s_red[1][q][p] = s;
    __syncthreads();
    s = ((s_red[1][0][p] + s_red[1][1][p]) + (s_red[1][2][p] + s_red[1][3][p]))
      + ((s_red[1][4][p] + s_red[1][5][p]) + (s_red[1][6][p] + s_red[1][7][p]));
    float lse = m + __logf(s);

    bool valid = n < lengths[b];
    float* po = out + ((size_t)b * 256 + q * 32) * NSEQ + n;
#pragma unroll
    for (int kk = 0; kk < 32; kk++) {
        float v = valid ? (o[kk] - lse) : 0.f;
        __builtin_nontemporal_store(v, &po[(size_t)kk * NSEQ]);
    }
}

extern "C" void kernel_launch(void* const* d_in, const int* in_sizes, int n_in,
                              void* d_out, int out_size, void* d_ws, size_t ws_size,
                              hipStream_t stream) {
    const float* x   = (const float*)d_in[0];
    const int* lens  = (const int*)d_in[1];
    const float* w0  = (const float*)d_in[2];
    const float* b0  = (const float*)d_in[3];
    const float* wf  = (const float*)d_in[4];
    const float* bf  = (const float*)d_in[5];
    const float* wg  = (const float*)d_in[6];
    const float* bg  = (const float*)d_in[7];
    const float* wa  = (const float*)d_in[8];
    const float* ba  = (const float*)d_in[9];
    const float* wo  = (const float*)d_in[10];
    const float* bo  = (const float*)d_in[11];
    float* out = (float*)d_out;

    float* hA = (float*)d_ws;                          // [B][N][16]
    float* hB = hA + (size_t)NB * NSEQ * NC;           // ping-pong (32 MiB total)

    k_layer0<<<dim3(LBLK), dim3(256), 0, stream>>>(x, w0, b0, hA);

    float* cur = hA;
    float* nxt = hB;
    for (int i = 1; i <= 29; i++) {
        int d = 1 << (i % 10);
        k_layer<<<dim3(QGRD), dim3(256), 0, stream>>>(cur, nxt,
                                         wf + (size_t)(i - 1) * NC * NC * 2,
                                         bf + (size_t)(i - 1) * NC,
                                         wg + (size_t)(i - 1) * NC * NC * 2,
                                         bg + (size_t)(i - 1) * NC, d);
        float* tmp = cur; cur = nxt; nxt = tmp;
    }

    dim3 fgrd(NB * (NSEQ / 64));
    k_final<<<fgrd, dim3(512), 0, stream>>>(cur, x, lens, wa, ba, wo, bo, out);
}